// Round 4
// baseline (256.372 us; speedup 1.0000x reference)
//
#include <hip/hip_runtime.h>

// Rx(theta) on qubit 0 (MSB of state index) of a 24-qubit state.
// Inputs: state_re [2^24] f32, state_im [2^24] f32, theta [1] f32.
// Output: [2, 2^24] f32 = stack(out_re, out_im).
//
//   s = sin(theta/2), c = cos(theta/2)
//   out0 = (c*a_re + s*b_im) + i(c*a_im - s*b_re)
//   out1 = (c*b_re + s*a_im) + i(c*b_im - s*a_re)
//
// R2 counters: 83 us @ 2.4 TB/s, FETCH=64MB (half of input -> L3 thrash by
// our own 128MiB output stream; 384MB footprint > 256MB L3).
// Fix: NON-TEMPORAL stores (output bypasses L3 -> inputs stay resident)
//      + 2x unroll with 8 grouped loads for deeper per-wave MLP.
// R3: __builtin_nontemporal_store needs a NATIVE vector type, not HIP's
//     float4 class -> use ext_vector_type(4) for the store path.

typedef float f32x4 __attribute__((ext_vector_type(4)));

constexpr int NV = 1 << 21;  // float4 elements per half (2^23 floats / 4)
constexpr int S  = 1 << 20;  // stride between a thread's two work items

__device__ __forceinline__ void rx_math(
    float c, float s,
    const f32x4& a_re, const f32x4& a_im,
    const f32x4& b_re, const f32x4& b_im,
    f32x4& o0_re, f32x4& o0_im, f32x4& o1_re, f32x4& o1_im)
{
    o0_re = c * a_re + s * b_im;
    o0_im = c * a_im - s * b_re;
    o1_re = c * b_re + s * a_im;
    o1_im = c * b_im - s * a_re;
}

__global__ __launch_bounds__(256) void rx_gate_kernel(
    const f32x4* __restrict__ sre,
    const f32x4* __restrict__ sim,
    const float* __restrict__ theta,
    f32x4* __restrict__ out)
{
    const int t = blockIdx.x * blockDim.x + threadIdx.x;  // [0, 2^20)
    const int j0 = t;
    const int j1 = t + S;

    // Uniform per wave; exact libm sin/cos.
    const float t2 = theta[0] * 0.5f;
    const float s = sinf(t2);
    const float c = cosf(t2);

    // 8 independent loads issued up front (plain loads: inputs should live
    // in L3 once NT stores stop thrashing it).
    const f32x4 a0_re = sre[j0];
    const f32x4 a0_im = sim[j0];
    const f32x4 b0_re = sre[j0 + NV];
    const f32x4 b0_im = sim[j0 + NV];
    const f32x4 a1_re = sre[j1];
    const f32x4 a1_im = sim[j1];
    const f32x4 b1_re = sre[j1 + NV];
    const f32x4 b1_im = sim[j1 + NV];

    f32x4 o0_re, o0_im, o1_re, o1_im;
    rx_math(c, s, a0_re, a0_im, b0_re, b0_im, o0_re, o0_im, o1_re, o1_im);

    // Output layout in float4 units:
    // [0:NV)=out0_re, [NV:2NV)=out1_re, [2NV:3NV)=out0_im, [3NV:4NV)=out1_im
    __builtin_nontemporal_store(o0_re, &out[j0]);
    __builtin_nontemporal_store(o1_re, &out[j0 + NV]);
    __builtin_nontemporal_store(o0_im, &out[j0 + 2 * NV]);
    __builtin_nontemporal_store(o1_im, &out[j0 + 3 * NV]);

    rx_math(c, s, a1_re, a1_im, b1_re, b1_im, o0_re, o0_im, o1_re, o1_im);

    __builtin_nontemporal_store(o0_re, &out[j1]);
    __builtin_nontemporal_store(o1_re, &out[j1 + NV]);
    __builtin_nontemporal_store(o0_im, &out[j1 + 2 * NV]);
    __builtin_nontemporal_store(o1_im, &out[j1 + 3 * NV]);
}

extern "C" void kernel_launch(void* const* d_in, const int* in_sizes, int n_in,
                              void* d_out, int out_size, void* d_ws, size_t ws_size,
                              hipStream_t stream) {
    const f32x4* sre   = (const f32x4*)d_in[0];
    const f32x4* sim   = (const f32x4*)d_in[1];
    const float* theta = (const float*)d_in[2];
    f32x4* out = (f32x4*)d_out;

    const int threads = 256;
    const int blocks  = S / threads;  // 2^20 / 256 = 4096 blocks = 16384 waves
    rx_gate_kernel<<<blocks, threads, 0, stream>>>(sre, sim, theta, out);
}

// Round 5
// 235.432 us; speedup vs baseline: 1.0889x; 1.0889x over previous
//
#include <hip/hip_runtime.h>

// Rx(theta) on qubit 0 (MSB of state index) of a 24-qubit state.
// Inputs: state_re [2^24] f32, state_im [2^24] f32, theta [1] f32.
// Output: [2, 2^24] f32 = stack(out_re, out_im).
//
//   s = sin(theta/2), c = cos(theta/2)
//   out0 = (c*a_re + s*b_im) + i(c*a_im - s*b_re)
//   out1 = (c*b_re + s*a_im) + i(c*b_im - s*a_re)
//
// R2: 83 us, 2.4 TB/s, FETCH=64MB, no conflicts, VALU 3% -> memory-rate wall.
// R4: NT stores + 2x unroll REGRESSED (93 us) -> NT store path is slow; reverted.
// R5 theory: known-good copy (1 load + 1 store stream/wave) hits 6.29 TB/s;
//   we ran 8 streams/wave. The gate factors into two independent 2-in/2-out
//   halves: {a_re,b_im} -> {o0_re,o1_im} and {a_im,b_re} -> {o0_im,o1_re}.
//   Split blocks into two families, each a 2-load/2-store streaming kernel
//   (copy-shaped). Traffic unchanged, per-wave streams halved.

typedef float f32x4 __attribute__((ext_vector_type(4)));

constexpr int NV = 1 << 21;  // float4 elements per half (2^23 floats / 4)

__global__ __launch_bounds__(256) void rx_gate_kernel(
    const f32x4* __restrict__ sre,
    const f32x4* __restrict__ sim,
    const float* __restrict__ theta,
    f32x4* __restrict__ out)
{
    // Uniform per wave; exact libm sin/cos.
    const float t2 = theta[0] * 0.5f;
    const float s = sinf(t2);
    const float c = cosf(t2);

    const int bid = blockIdx.x;
    const int i   = (bid >> 1) * blockDim.x + threadIdx.x;  // [0, NV)

    // Output layout in float4 units:
    // [0:NV)=out0_re, [NV:2NV)=out1_re, [2NV:3NV)=out0_im, [3NV:4NV)=out1_im
    if ((bid & 1) == 0) {
        // Family A: reads {a_re, b_im}, writes {o0_re, o1_im}
        const f32x4 a_re = sre[i];
        const f32x4 b_im = sim[i + NV];
        const f32x4 o0_re = c * a_re + s * b_im;
        const f32x4 o1_im = c * b_im - s * a_re;
        out[i]          = o0_re;
        out[i + 3 * NV] = o1_im;
    } else {
        // Family B: reads {a_im, b_re}, writes {o0_im, o1_re}
        const f32x4 a_im = sim[i];
        const f32x4 b_re = sre[i + NV];
        const f32x4 o0_im = c * a_im - s * b_re;
        const f32x4 o1_re = c * b_re + s * a_im;
        out[i + 2 * NV] = o0_im;
        out[i + NV]     = o1_re;
    }
}

extern "C" void kernel_launch(void* const* d_in, const int* in_sizes, int n_in,
                              void* d_out, int out_size, void* d_ws, size_t ws_size,
                              hipStream_t stream) {
    const f32x4* sre   = (const f32x4*)d_in[0];
    const f32x4* sim   = (const f32x4*)d_in[1];
    const float* theta = (const float*)d_in[2];
    f32x4* out = (f32x4*)d_out;

    const int threads = 256;
    const int blocks  = 2 * (NV / threads);  // 2 families x 8192 = 16384 blocks
    rx_gate_kernel<<<blocks, threads, 0, stream>>>(sre, sim, theta, out);
}

// Round 6
// 235.337 us; speedup vs baseline: 1.0894x; 1.0004x over previous
//
#include <hip/hip_runtime.h>

// Rx(theta) on qubit 0 (MSB of state index) of a 24-qubit state.
// Inputs: state_re [2^24] f32, state_im [2^24] f32, theta [1] f32.
// Output: [2, 2^24] f32 = stack(out_re, out_im).
//
//   s = sin(theta/2), c = cos(theta/2)
//   out0 = (c*a_re + s*b_im) + i(c*a_im - s*b_re)
//   out1 = (c*b_re + s*a_im) + i(c*b_im - s*a_re)
//
// R2: 83 us, 2.4 TB/s, FETCH=64MB (exactly half of input), VALU 3%.
// R5: two-family split (2-load/2-store per wave) -> ~74 us. Topology helps.
// R6 theory: inputs are L3-resident at kernel start (harness re-upload);
//   our own store-allocations evict them at a rate matched to our reads
//   -> the exact-half FETCH signature. Outputs are never re-read, so
//   store-allocation is pure L3 poison. Fix: NON-TEMPORAL stores only
//   (single variable vs R5; R4's NT test was confounded by 8 store
//   streams/wave). Plain loads. Expect FETCH -> ~0, kernel 35-50 us.

typedef float f32x4 __attribute__((ext_vector_type(4)));

constexpr int NV = 1 << 21;  // float4 elements per half (2^23 floats / 4)

__global__ __launch_bounds__(256) void rx_gate_kernel(
    const f32x4* __restrict__ sre,
    const f32x4* __restrict__ sim,
    const float* __restrict__ theta,
    f32x4* __restrict__ out)
{
    // Uniform per wave; exact libm sin/cos.
    const float t2 = theta[0] * 0.5f;
    const float s = sinf(t2);
    const float c = cosf(t2);

    const int bid = blockIdx.x;
    const int i   = (bid >> 1) * blockDim.x + threadIdx.x;  // [0, NV)

    // Output layout in float4 units:
    // [0:NV)=out0_re, [NV:2NV)=out1_re, [2NV:3NV)=out0_im, [3NV:4NV)=out1_im
    if ((bid & 1) == 0) {
        // Family A: reads {a_re, b_im}, writes {o0_re, o1_im}
        const f32x4 a_re = sre[i];
        const f32x4 b_im = sim[i + NV];
        const f32x4 o0_re = c * a_re + s * b_im;
        const f32x4 o1_im = c * b_im - s * a_re;
        __builtin_nontemporal_store(o0_re, &out[i]);
        __builtin_nontemporal_store(o1_im, &out[i + 3 * NV]);
    } else {
        // Family B: reads {a_im, b_re}, writes {o0_im, o1_re}
        const f32x4 a_im = sim[i];
        const f32x4 b_re = sre[i + NV];
        const f32x4 o0_im = c * a_im - s * b_re;
        const f32x4 o1_re = c * b_re + s * a_im;
        __builtin_nontemporal_store(o0_im, &out[i + 2 * NV]);
        __builtin_nontemporal_store(o1_re, &out[i + NV]);
    }
}

extern "C" void kernel_launch(void* const* d_in, const int* in_sizes, int n_in,
                              void* d_out, int out_size, void* d_ws, size_t ws_size,
                              hipStream_t stream) {
    const f32x4* sre   = (const f32x4*)d_in[0];
    const f32x4* sim   = (const f32x4*)d_in[1];
    const float* theta = (const float*)d_in[2];
    f32x4* out = (f32x4*)d_out;

    const int threads = 256;
    const int blocks  = 2 * (NV / threads);  // 2 families x 8192 = 16384 blocks
    rx_gate_kernel<<<blocks, threads, 0, stream>>>(sre, sim, theta, out);
}